// Round 1
// 374.767 us; speedup vs baseline: 1.0176x; 1.0176x over previous
//
#include <hip/hip_runtime.h>
#include <hip/hip_fp16.h>
#include <hip/hip_bf16.h>

#define BATCH   256
#define DIMS    64
#define LEVELS  100
#define HVD     10000
#define WH      64        // h-tile columns per block
#define NHT     157       // ceil(HVD/WH); tile 156 has 16 valid cols
#define DSPLIT  8
#define DPER    8
#define TPB     256       // 4 waves
#define FTPB    1024      // finish: 16 waves -> 4 waves/SIMD of TLP
#define CHUNK_FLOATS (LEVELS * WH)            // 6400 floats = 25.6 KB
#define NSTG    25        // staging instrs per chunk (100 rows / 4 rows per instr)

typedef unsigned int   uint;
typedef unsigned short ushort;

// d_ws layout: [0, 40.96 MB) bf16 partial [DSPLIT][BATCH][HVD]
//   (prm buffer eliminated: params are computed in-kernel from x)

static __device__ __forceinline__ ushort f2bf(float f) {
    __hip_bfloat16 h = __float2bfloat16(f);   // RNE
    return *reinterpret_cast<ushort*>(&h);
}

// ---------------------------------------------------------------------------
// Encode: block = (h-tile 64 cols, d-split of 8 dims) x ALL 256 batches.
// NEVER-DRAIN K-loop: double-buffered LDS chunks staged via global_load_lds,
// raw s_barrier + manual s_waitcnt vmcnt(N) so the next chunk's loads stay
// in flight through every compute phase (HBM duty cycle ~100%).
// Per wave, loads/chunk = 7 (wave 0) or 6 (waves 1-3); waiting vmcnt(6)
// completes the current chunk for all waves (wave 0 over-waits by 1 load).
// The K-loop issues NO other vmcnt ops (params computed in the prologue and
// fully drained by the __syncthreads below), so the manual counts are exact.
// Each base byte fetched once, coalesced.
//
// SETUP IS FUSED: thread tid owns batch b=tid; its 8 dims d0..d0+7 are
// contiguous in x -> two float4 loads, pack fp16(alpha)|lo<<16|hi<<24 into
// s_prm. ~100 cycles per block, replaces a whole kernel launch + prm
// global round-trip. x is 64 KB -> L2/L3-resident broadcast across blocks.
// ---------------------------------------------------------------------------
__global__ __launch_bounds__(TPB, 2) void encode_kernel(
    const float* __restrict__ x,
    const float* __restrict__ base,
    ushort*     __restrict__ partial)      // bf16 [DSPLIT][BATCH][HVD]
{
    __shared__ float s_buf[2][CHUNK_FLOATS];   // 51.2 KB
    __shared__ uint  s_prm[DPER][BATCH];       // 8 KB

    const int tid   = threadIdx.x;
    const int w     = tid >> 6;            // wave 0..3
    const int lane  = tid & 63;
    const int htile = blockIdx.x;
    const int split = blockIdx.y;
    const int h0    = htile * WH;
    const int d0    = split * DPER;
    const int wvalid = (HVD - h0) < WH ? (HVD - h0) : WH;

    // Fused param setup (b = tid, d = d0 + k). Drained by the __syncthreads
    // below, so these loads never pollute the K-loop's vmcnt bookkeeping.
    {
        const float4* xr = (const float4*)(x + (size_t)tid * DIMS + d0);
        const float4 xa = xr[0];
        const float4 xb = xr[1];
        const float xv[8] = { xa.x, xa.y, xa.z, xa.w, xb.x, xb.y, xb.z, xb.w };
        #pragma unroll
        for (int k = 0; k < DPER; ++k) {
            float xn = fminf(fmaxf(xv[k] * (float)(LEVELS - 1), 0.0f),
                             (float)(LEVELS - 1));
            float fl = floorf(xn);
            int   lo = (int)fl;
            int   hi = lo < LEVELS - 1 ? lo + 1 : LEVELS - 1;
            uint abits = (uint)__half_as_ushort(__float2half(xn - fl));
            s_prm[k][tid] = abits | ((uint)lo << 16) | ((uint)hi << 24);
        }
    }
    __syncthreads();   // params visible; all counters drained

    const int srow = lane >> 4;            // staging: row within 4-row group
    const int scol = (lane & 15) * 4;      // staging: float col
    const float* srcdim = base + (size_t)d0 * LEVELS * HVD + h0;

    auto issue_chunk = [&](int dc, int bufidx) {
        const float* src = srcdim + (size_t)dc * LEVELS * HVD;
        float* dst = &s_buf[bufidx][0];
        for (int p = w; p < NSTG; p += 4) {          // wave0:7, waves1-3:6
            const float* g = src + (size_t)(4 * p + srow) * HVD + scol;
            if (scol < wvalid) {                      // lane mask; instr still issues
                __builtin_amdgcn_global_load_lds(
                    (const __attribute__((address_space(1))) uint*)g,
                    (__attribute__((address_space(3))) uint*)(dst + p * 4 * WH),
                    16, 0, 0);
            }
        }
    };

    issue_chunk(0, 0);
    issue_chunk(1, 1);

    const int sub   = lane >> 5;           // batch sub 0/1
    const int p2    = lane & 31;           // col pair (2 floats)
    const int pb    = p2 * 8;              // byte offset within a 256 B row
    const int bbase = w * 64;              // this wave's 64 batches

    float2 acc[32];
    #pragma unroll
    for (int j = 0; j < 32; ++j) acc[j] = make_float2(0.f, 0.f);

    #pragma unroll 1
    for (int dc = 0; dc < DPER; ++dc) {
        // Wait for chunk dc only; chunk dc+1's loads remain in flight.
        if (dc < DPER - 1) asm volatile("s_waitcnt vmcnt(6)" ::: "memory");
        else               asm volatile("s_waitcnt vmcnt(0)" ::: "memory");
        __builtin_amdgcn_s_barrier();      // all waves' chunk-dc portions landed

        const char* buf = (const char*)&s_buf[dc & 1][0];
        #pragma unroll
        for (int j = 0; j < 32; ++j) {
            uint2 pp = *(const uint2*)&s_prm[dc][bbase + 2 * j];  // b64 broadcast
            const uint pk = sub ? pp.y : pp.x;
            const float a = __half2float(__ushort_as_half((ushort)(pk & 0xffffu)));
            const int olo = (int)((pk >> 16) & 0xffu) << 8;   // lo * 256 B
            const int ohi = (int)(pk >> 24) << 8;             // hi * 256 B
            const float2 vlo = *(const float2*)(buf + olo + pb);
            const float2 vhi = *(const float2*)(buf + ohi + pb);
            const float wl = 1.0f - a;
            acc[j].x += wl * vlo.x + a * vhi.x;
            acc[j].y += wl * vlo.y + a * vhi.y;
        }
        asm volatile("" ::: "memory");     // pin reads before the reuse barrier
        __builtin_amdgcn_s_barrier();      // all waves done reading buf[dc&1]
        if (dc < DPER - 2) issue_chunk(dc + 2, dc & 1);   // overwrite freed buffer
    }

    // bf16 partial store: per instr, 2 batch-rows x 128 B contiguous.
    if (p2 * 2 < wvalid) {
        #pragma unroll
        for (int j = 0; j < 32; ++j) {
            const int b = bbase + 2 * j + sub;
            const uint pk = (uint)f2bf(acc[j].x) | ((uint)f2bf(acc[j].y) << 16);
            *(uint*)(partial + ((size_t)split * BATCH + b) * (size_t)HVD + h0 + p2 * 2) = pk;
        }
    }
}

// ---------------------------------------------------------------------------
// Finish: SINGLE-PASS. Per batch row: sum the 8 bf16 partials into registers
// (<=16 floats/thread), block-reduce sum-of-squares, scale in-register,
// store out exactly once. Eliminates the old write->re-read->re-write of out
// (30.7 MB -> 10.2 MB of out traffic) and raises TLP from 1 to 4 waves/SIMD.
// 16 B uint4 loads: 8 bf16 per load per sp-stream.
// ---------------------------------------------------------------------------
__global__ __launch_bounds__(FTPB) void finish_kernel(
    const ushort* __restrict__ partial,    // bf16 [DSPLIT][BATCH][HVD]
    float* __restrict__ out)               // fp32 [BATCH][HVD]
{
    const int b   = blockIdx.x;
    const int tid = threadIdx.x;

    // HVD/8 = 1250 groups of 8 floats; k=0: g=tid, k=1: g=tid+1024 (<1250)
    float4 v0[2], v1[2];
    float  ss = 0.f;
    #pragma unroll
    for (int k = 0; k < 2; ++k) {
        const int g = k * FTPB + tid;
        float4 a = make_float4(0.f, 0.f, 0.f, 0.f);
        float4 c = make_float4(0.f, 0.f, 0.f, 0.f);
        if (g < HVD / 8) {
            #pragma unroll
            for (int sp = 0; sp < DSPLIT; ++sp) {
                const uint4 u = *(const uint4*)(partial +
                    ((size_t)sp * BATCH + b) * (size_t)HVD + (size_t)g * 8);
                a.x += __uint_as_float(u.x << 16);
                a.y += __uint_as_float(u.x & 0xffff0000u);
                a.z += __uint_as_float(u.y << 16);
                a.w += __uint_as_float(u.y & 0xffff0000u);
                c.x += __uint_as_float(u.z << 16);
                c.y += __uint_as_float(u.z & 0xffff0000u);
                c.z += __uint_as_float(u.w << 16);
                c.w += __uint_as_float(u.w & 0xffff0000u);
            }
            ss += a.x * a.x + a.y * a.y + a.z * a.z + a.w * a.w
                + c.x * c.x + c.y * c.y + c.z * c.z + c.w * c.w;
        }
        v0[k] = a; v1[k] = c;
    }

    __shared__ float red[FTPB];
    red[tid] = ss;
    __syncthreads();
    #pragma unroll
    for (int sh = FTPB / 2; sh > 0; sh >>= 1) {
        if (tid < sh) red[tid] += red[tid + sh];
        __syncthreads();
    }
    const float inv = rsqrtf(red[0]);

    #pragma unroll
    for (int k = 0; k < 2; ++k) {
        const int g = k * FTPB + tid;
        if (g < HVD / 8) {
            float4 a = v0[k], c = v1[k];
            a.x *= inv; a.y *= inv; a.z *= inv; a.w *= inv;
            c.x *= inv; c.y *= inv; c.z *= inv; c.w *= inv;
            *(float4*)(out + (size_t)b * HVD + (size_t)g * 8)     = a;
            *(float4*)(out + (size_t)b * HVD + (size_t)g * 8 + 4) = c;
        }
    }
}

extern "C" void kernel_launch(void* const* d_in, const int* in_sizes, int n_in,
                              void* d_out, int out_size, void* d_ws, size_t ws_size,
                              hipStream_t stream)
{
    const float* x    = (const float*)d_in[0];   // (256, 64)
    const float* base = (const float*)d_in[1];   // (64, 100, 10000)
    float*       out  = (float*)d_out;           // (256, 10000)
    ushort*      part = (ushort*)d_ws;           // bf16 partials

    dim3 grid(NHT, DSPLIT);
    encode_kernel<<<grid, TPB, 0, stream>>>(x, base, part);
    finish_kernel<<<BATCH, FTPB, 0, stream>>>(part, out);
}